// Round 12
// baseline (298.917 us; speedup 1.0000x reference)
//
#include <hip/hip_runtime.h>
#include <hip/hip_bf16.h>
#include <cstdint>
#include <cstddef>

#define NB 2
#define NH 8
#define BHN 16          // NB*NH
#define NN 3072         // tokens
#define CC 256          // channels
#define DD 32           // head dim
#define OUTW 3104       // NN + DD
#define VW 48           // padded v2p width (38 -> 48)
#define KP 384          // NH*VW, padded K for proj GEMM

typedef __attribute__((ext_vector_type(8))) __bf16 bf16x8;
typedef __attribute__((ext_vector_type(4))) short short4v;
typedef __attribute__((ext_vector_type(4))) float f32x4;

static __device__ __forceinline__ unsigned short f2bf(float f) {
    __hip_bfloat16 h = __float2bfloat16(f);
    return *reinterpret_cast<unsigned short*>(&h);
}

static __device__ __forceinline__ bf16x8 ldb8(const unsigned short* p) {
    return *(const bf16x8*)p;
}

static __device__ __forceinline__ f32x4 mfma16(bf16x8 a, bf16x8 b, f32x4 c) {
    return __builtin_amdgcn_mfma_f32_16x16x32_bf16(a, b, c, 0, 0, 0);
}

static __device__ __forceinline__ float bfhi2f(unsigned u) {
    union { unsigned u; float f; } v; v.u = u & 0xffff0000u; return v.f;
}
static __device__ __forceinline__ float bflo2f(unsigned u) {
    union { unsigned u; float f; } v; v.u = u << 16; return v.f;
}

// ---------------------------------------------------------------------------
// prep
// ---------------------------------------------------------------------------
__global__ __launch_bounds__(256) void prep_kernel(
    const float* __restrict__ x1, const float* __restrict__ x2,
    const float* __restrict__ Wq, const float* __restrict__ Wkv,
    const float* __restrict__ Wpf,
    unsigned short* __restrict__ x1b, unsigned short* __restrict__ x2b,
    unsigned short* __restrict__ Wt, unsigned short* __restrict__ Wpft,
    unsigned short* __restrict__ v2pT)
{
    int i = blockIdx.x * 256 + threadIdx.x;
    const int S_X = NB * NN * CC;
    if (i < S_X) { x1b[i] = f2bf(x1[i]); return; }
    i -= S_X;
    if (i < S_X) { x2b[i] = f2bf(x2[i]); return; }
    i -= S_X;
    const int S_WT = 768 * CC;
    if (i < S_WT) {
        int j = i >> 8, kk = i & 255;
        float w = (j < 256) ? Wq[kk * 256 + j] : Wkv[kk * 512 + (j - 256)];
        Wt[i] = f2bf(w);
        return;
    }
    i -= S_WT;
    const int S_WP = 256 * KP;
    if (i < S_WP) {
        int c2 = i / KP, t = i - c2 * KP;
        int h = t / VW, cc = t - h * VW;
        unsigned short v = 0;
        if (cc < 38) v = f2bf(Wpf[(h * 38 + cc) * 256 + c2]);
        Wpft[i] = v;
        return;
    }
    i -= S_WP;
    const int S_POS = BHN * 16 * NN;
    if (i < S_POS) {
        int n = i % NN;
        int r = i / NN;
        int bh = r >> 4;
        int c = (r & 15) + 32;
        float val = 0.f;
        if (c < 38) {
            float p3 = -1.f + 2.f * (float)(n % 48) / 47.f;
            float p4 = -1.f + 2.f * (float)(n / 48) / 63.f;
            float pv[6] = { p3 * p3, p4 * p4, p3 * p4, p3, p4, 1.f };
            val = pv[c - 32];
        }
        v2pT[((size_t)bh * VW + c) * NN + n] = f2bf(val);
    }
}

// ---------------------------------------------------------------------------
// qkv
// ---------------------------------------------------------------------------
__global__ __launch_bounds__(256) void qkv_kernel(
    const unsigned short* __restrict__ x1b, const unsigned short* __restrict__ x2b,
    const unsigned short* __restrict__ Wt,
    unsigned short* __restrict__ qbh, unsigned short* __restrict__ kbh,
    unsigned short* __restrict__ v2pT)
{
    int rt = blockIdx.x, ct = blockIdx.y;
    int wv = threadIdx.x >> 6, lane = threadIdx.x & 63;
    int g = lane >> 4, q = lane & 15;
    int row0 = rt * 64 + wv * 16;
    const unsigned short* A = (ct < 4) ? x1b : x2b;
    const unsigned short* arow = A + (size_t)(row0 + q) * CC + g * 8;
    const unsigned short* brow = Wt + (size_t)(ct * 64 + q) * CC + g * 8;
    f32x4 acc[4];
    #pragma unroll
    for (int cb = 0; cb < 4; ++cb) acc[cb] = f32x4{0.f, 0.f, 0.f, 0.f};
    for (int k0 = 0; k0 < CC; k0 += 32) {
        bf16x8 af = ldb8(arow + k0);
        #pragma unroll
        for (int cb = 0; cb < 4; ++cb)
            acc[cb] = mfma16(af, ldb8(brow + (size_t)cb * 16 * CC + k0), acc[cb]);
    }
    int b = row0 / NN, nb = row0 % NN;
    #pragma unroll
    for (int cb = 0; cb < 4; ++cb) {
        int jj = ct * 64 + cb * 16 + q;
        #pragma unroll
        for (int r = 0; r < 4; ++r) {
            int n = nb + 4 * g + r;
            unsigned short bv = f2bf(acc[cb][r]);
            if (jj < 256) {
                int h = jj >> 5, c = jj & 31;
                qbh[(size_t)((b * NH + h) * NN + n) * DD + c] = bv;
            } else if (jj < 512) {
                int jk = jj - 256; int h = jk >> 5, c = jk & 31;
                kbh[(size_t)((b * NH + h) * NN + n) * DD + c] = bv;
            } else {
                int jv = jj - 512; int h = jv >> 5, c = jv & 31;
                v2pT[(size_t)((b * NH + h) * VW + c) * NN + n] = bv;
            }
        }
    }
}

// ---------------------------------------------------------------------------
// fused attention v11b (v11 with store-loop bound fixed: 12 chunks, not 24).
// block = 512 thr (8 waves) = ONE 16-row q-tile with the FULL S^T row set in
// LDS ([16][3072] bf16 = 96 KB). Waves split m 8-ways. Pass A: partial l ->
// LDS reduce. Pass B: fill wave-private column slices (exp2-fma, XOR-swizzle,
// PV-from-LDS). Then each wave streams 2 WHOLE ROWS sequentially (12 NT
// dwordx4 = 12 KB per row, rows adjacent) — fill-like long sequential runs.
// y^T partials reduced via separate LDS scratch behind an lgkmcnt-only
// barrier so NT stores stay in flight past block end (next block's compute
// overlaps this block's store drain; s_endpgm does not drain vmcnt).
// ---------------------------------------------------------------------------
__global__ __launch_bounds__(512) void attn_kernel(
    const unsigned short* __restrict__ qbh, const unsigned short* __restrict__ kbh,
    const unsigned short* __restrict__ v2pT,
    float* __restrict__ out, unsigned short* __restrict__ yacc)
{
    __shared__ unsigned short tile[16][3072];    // 96 KB
    __shared__ float lred[8][16];
    __shared__ float yl[8][48][17];              // 26 KB
    const float C = 0.17677669529663687f * 1.4426950408889634f;  // scale*log2e

    int id = blockIdx.x;
    int bh = id & 15;
    int tl = id >> 4;                  // 0..191
    int qrow = tl * 16;

    int wv = threadIdx.x >> 6, lane = threadIdx.x & 63;
    int g = lane >> 4, q = lane & 15;
    int mb = wv * 384;                 // this wave's m-slice

    bf16x8 qf = ldb8(qbh + (size_t)(bh * NN + qrow + q) * DD + g * 8);
    const unsigned short* kbase = kbh + (size_t)bh * NN * DD;
    const unsigned short* vbase = v2pT + (size_t)bh * VW * NN;

    // ---- pass A: partial row sums over [mb, mb+384) ----
    float l = 0.f;
    {
        bf16x8 kf0 = ldb8(kbase + (size_t)(mb + q) * DD + g * 8);
        bf16x8 kf1 = ldb8(kbase + (size_t)(mb + 16 + q) * DD + g * 8);
        for (int it = 0; it < 12; ++it) {
            int m0 = mb + it * 32;
            bf16x8 kn0 = ldb8(kbase + (size_t)(m0 + 32 + q) * DD + g * 8);
            bf16x8 kn1 = ldb8(kbase + (size_t)(m0 + 48 + q) * DD + g * 8);
            f32x4 z = {0.f, 0.f, 0.f, 0.f};
            f32x4 s0 = mfma16(kf0, qf, z);
            f32x4 s1 = mfma16(kf1, qf, z);
            #pragma unroll
            for (int r = 0; r < 4; ++r)
                l += exp2f(s0[r] * C) + exp2f(s1[r] * C);
            kf0 = kn0; kf1 = kn1;
        }
    }
    l += __shfl_xor(l, 16, 64);
    l += __shfl_xor(l, 32, 64);
    if (lane < 16) lred[wv][q] = l;
    __syncthreads();
    float lt = 0.f;
    #pragma unroll
    for (int w = 0; w < 8; ++w) lt += lred[w][q];
    float nl2 = -__log2f(lt);                  // p = exp2(s*C + nl2)

    // ---- pass B: fill tile cols [mb, mb+384), accumulate PV partials ----
    f32x4 yt0 = {0.f,0.f,0.f,0.f}, yt1 = yt0, yt2 = yt0;
    char* prow = (char*)&tile[0][0] + q * 6144;  // this thread's row
    unsigned swq = (unsigned)((q & 7) << 4);     // XOR bank swizzle (bits 4..6)
    int wb = wv * 768;                           // wave's byte slice in a row

    {
        bf16x8 kf0 = ldb8(kbase + (size_t)(mb + q) * DD + g * 8);
        bf16x8 kf1 = ldb8(kbase + (size_t)(mb + 16 + q) * DD + g * 8);
        bf16x8 vf0 = ldb8(vbase + (size_t)(q) * NN + mb + g * 8);
        bf16x8 vf1 = ldb8(vbase + (size_t)(16 + q) * NN + mb + g * 8);
        bf16x8 vf2 = ldb8(vbase + (size_t)(32 + q) * NN + mb + g * 8);
        #pragma unroll 4
        for (int it2 = 0; it2 < 12; ++it2) {
            int m0 = mb + it2 * 32;
            int mn = m0 + 32;    // tail prefetch reads stay inside ws: ok
            bf16x8 kn0 = ldb8(kbase + (size_t)(mn + q) * DD + g * 8);
            bf16x8 kn1 = ldb8(kbase + (size_t)(mn + 16 + q) * DD + g * 8);
            bf16x8 vn0 = ldb8(vbase + (size_t)(q) * NN + mn + g * 8);
            bf16x8 vn1 = ldb8(vbase + (size_t)(16 + q) * NN + mn + g * 8);
            bf16x8 vn2 = ldb8(vbase + (size_t)(32 + q) * NN + mn + g * 8);

            f32x4 z = {0.f, 0.f, 0.f, 0.f};
            f32x4 s0 = mfma16(kf0, qf, z);
            f32x4 s1 = mfma16(kf1, qf, z);
            short4v pk0, pk1;
            #pragma unroll
            for (int r = 0; r < 4; ++r) {
                pk0[r] = (short)f2bf(exp2f(__builtin_fmaf(s0[r], C, nl2)));
                pk1[r] = (short)f2bf(exp2f(__builtin_fmaf(s1[r], C, nl2)));
            }
            unsigned b0 = (unsigned)(wb + it2 * 64 + 8 * g);
            *(short4v*)(prow + (b0 ^ swq)) = pk0;
            *(short4v*)(prow + ((b0 + 32) ^ swq)) = pk1;
            asm volatile("s_waitcnt lgkmcnt(0)" ::: "memory");
            __builtin_amdgcn_sched_barrier(0);
            bf16x8 pf = *(const bf16x8*)(prow + ((unsigned)(wb + it2 * 64 + 16 * g) ^ swq));
            yt0 = mfma16(vf0, pf, yt0);
            yt1 = mfma16(vf1, pf, yt1);
            yt2 = mfma16(vf2, pf, yt2);
            kf0 = kn0; kf1 = kn1; vf0 = vn0; vf1 = vn1; vf2 = vn2;
        }
    }
    __syncthreads();    // whole tile complete

    // ---- store phase: wave wv streams rows 2wv, 2wv+1 sequentially ----
    // row = 3072 bf16 = 6144 B LDS = 12 x 512 B reads -> 12 x 1 KB f32 NT
    // stores = 12 KB sequential per row; the wave's two rows are adjacent.
    #pragma unroll
    for (int j = 0; j < 2; ++j) {
        int r = wv * 2 + j;
        const char* rsrc = (const char*)&tile[0][0] + r * 6144;
        unsigned swr = (unsigned)((r & 7) << 4);
        float* dst = out + (size_t)(bh * NN + qrow + r) * OUTW + lane * 4;
        #pragma unroll
        for (int c = 0; c < 12; ++c) {
            unsigned off = ((unsigned)(c * 512 + lane * 8)) ^ swr;
            unsigned long long d = *(const unsigned long long*)(rsrc + off);
            unsigned dlo = (unsigned)d, dhi = (unsigned)(d >> 32);
            f32x4 v;
            v[0] = bflo2f(dlo); v[1] = bfhi2f(dlo);
            v[2] = bflo2f(dhi); v[3] = bfhi2f(dhi);
            __builtin_nontemporal_store(v, (f32x4*)(dst + c * 256));
        }
    }

    // ---- cross-wave y^T reduce via separate scratch (no vmcnt drain) ----
    {
        f32x4 yts[3] = { yt0, yt1, yt2 };
        #pragma unroll
        for (int cb = 0; cb < 3; ++cb)
            #pragma unroll
            for (int r = 0; r < 4; ++r)
                yl[wv][cb * 16 + 4 * g + r][q] = yts[cb][r];
    }
    // barrier WITHOUT vmcnt drain: LDS ordering only (stores stay in flight)
    asm volatile("s_waitcnt lgkmcnt(0)\n\ts_barrier" ::: "memory");
    {
        int t = threadIdx.x;
        if (t < 192) {
            int c0 = (t >> 4) << 2;      // 0,4,...,44
            int qq = t & 15;
            int b = bh >> 3, h = bh & 7;
            short4v pk;
            #pragma unroll
            for (int rr = 0; rr < 4; ++rr) {
                int c = c0 + rr;
                float s = 0.f;
                #pragma unroll
                for (int w = 0; w < 8; ++w) s += yl[w][c][qq];
                pk[rr] = (short)f2bf(s);
            }
            *(short4v*)(yacc + (size_t)(b * NN + qrow + qq) * KP + h * VW + c0) = pk;
        }
    }
}

// ---------------------------------------------------------------------------
// proj
// ---------------------------------------------------------------------------
__global__ __launch_bounds__(256) void proj_kernel(
    const unsigned short* __restrict__ yacc, const unsigned short* __restrict__ Wpft,
    const float* __restrict__ bpf, float* __restrict__ out)
{
    int rt = blockIdx.x, ct = blockIdx.y;
    int wv = threadIdx.x >> 6, lane = threadIdx.x & 63;
    int g = lane >> 4, q = lane & 15;
    int row0 = rt * 64 + wv * 16;
    const unsigned short* arow = yacc + (size_t)(row0 + q) * KP + g * 8;
    const unsigned short* b0 = Wpft + (size_t)(ct * 64 + q) * KP + g * 8;
    f32x4 acc[4];
    #pragma unroll
    for (int cb = 0; cb < 4; ++cb) acc[cb] = f32x4{0.f, 0.f, 0.f, 0.f};
    for (int k0 = 0; k0 < KP; k0 += 32) {
        bf16x8 af = ldb8(arow + k0);
        #pragma unroll
        for (int cb = 0; cb < 4; ++cb)
            acc[cb] = mfma16(af, ldb8(b0 + (size_t)cb * 16 * KP + k0), acc[cb]);
    }
    int b = row0 / NN, nb = row0 % NN;
    #pragma unroll
    for (int cb = 0; cb < 4; ++cb) {
        int c2 = ct * 64 + cb * 16 + q;
        float bias = bpf[c2];
        int h = c2 >> 5, c = c2 & 31;
        float* obase = out + (size_t)((b * NH + h) * NN) * OUTW + NN + c;
        #pragma unroll
        for (int r = 0; r < 4; ++r) {
            int n = nb + 4 * g + r;
            __builtin_nontemporal_store(acc[cb][r] + bias, &obase[(size_t)n * OUTW]);
        }
    }
}

// ---------------------------------------------------------------------------
extern "C" void kernel_launch(void* const* d_in, const int* in_sizes, int n_in,
                              void* d_out, int out_size, void* d_ws, size_t ws_size,
                              hipStream_t stream)
{
    (void)in_sizes; (void)n_in; (void)out_size; (void)ws_size;
    const float* x1  = (const float*)d_in[0];
    const float* x2  = (const float*)d_in[1];
    const float* Wq  = (const float*)d_in[2];
    const float* Wkv = (const float*)d_in[3];
    const float* Wpf = (const float*)d_in[4];
    const float* bpf = (const float*)d_in[5];
    float* out = (float*)d_out;
    char* ws = (char*)d_ws;

    unsigned short* x1b  = (unsigned short*)(ws + 0);
    unsigned short* x2b  = (unsigned short*)(ws + 3145728);
    unsigned short* Wt   = (unsigned short*)(ws + 6291456);
    unsigned short* Wpft = (unsigned short*)(ws + 6684672);
    unsigned short* qbh  = (unsigned short*)(ws + 6881280);
    unsigned short* kbh  = (unsigned short*)(ws + 10027008);
    unsigned short* v2pT = (unsigned short*)(ws + 13172736);
    unsigned short* yacc = (unsigned short*)(ws + 17891328);

    prep_kernel<<<16512, 256, 0, stream>>>(x1, x2, Wq, Wkv, Wpf, x1b, x2b, Wt, Wpft, v2pT);
    qkv_kernel<<<dim3(96, 12), 256, 0, stream>>>(x1b, x2b, Wt, qbh, kbh, v2pT);
    attn_kernel<<<3072, 512, 0, stream>>>(qbh, kbh, v2pT, out, yacc);
    proj_kernel<<<dim3(96, 4), 256, 0, stream>>>(yacc, Wpft, bpf, out);
}

// Round 13
// 240.615 us; speedup vs baseline: 1.2423x; 1.2423x over previous
//
#include <hip/hip_runtime.h>
#include <hip/hip_bf16.h>
#include <cstdint>
#include <cstddef>

#define NB 2
#define NH 8
#define BHN 16          // NB*NH
#define NN 3072         // tokens
#define CC 256          // channels
#define DD 32           // head dim
#define OUTW 3104       // NN + DD
#define VW 48           // padded v2p width (38 -> 48)
#define KP 384          // NH*VW, padded K for proj GEMM

typedef __attribute__((ext_vector_type(8))) __bf16 bf16x8;
typedef __attribute__((ext_vector_type(4))) short short4v;
typedef __attribute__((ext_vector_type(4))) float f32x4;

static __device__ __forceinline__ unsigned short f2bf(float f) {
    __hip_bfloat16 h = __float2bfloat16(f);
    return *reinterpret_cast<unsigned short*>(&h);
}

static __device__ __forceinline__ bf16x8 ldb8(const unsigned short* p) {
    return *(const bf16x8*)p;
}

static __device__ __forceinline__ f32x4 mfma16(bf16x8 a, bf16x8 b, f32x4 c) {
    return __builtin_amdgcn_mfma_f32_16x16x32_bf16(a, b, c, 0, 0, 0);
}

static __device__ __forceinline__ float bfhi2f(unsigned u) {
    union { unsigned u; float f; } v; v.u = u & 0xffff0000u; return v.f;
}
static __device__ __forceinline__ float bflo2f(unsigned u) {
    union { unsigned u; float f; } v; v.u = u << 16; return v.f;
}

// ---------------------------------------------------------------------------
// prep
// ---------------------------------------------------------------------------
__global__ __launch_bounds__(256) void prep_kernel(
    const float* __restrict__ x1, const float* __restrict__ x2,
    const float* __restrict__ Wq, const float* __restrict__ Wkv,
    const float* __restrict__ Wpf,
    unsigned short* __restrict__ x1b, unsigned short* __restrict__ x2b,
    unsigned short* __restrict__ Wt, unsigned short* __restrict__ Wpft,
    unsigned short* __restrict__ v2pT)
{
    int i = blockIdx.x * 256 + threadIdx.x;
    const int S_X = NB * NN * CC;
    if (i < S_X) { x1b[i] = f2bf(x1[i]); return; }
    i -= S_X;
    if (i < S_X) { x2b[i] = f2bf(x2[i]); return; }
    i -= S_X;
    const int S_WT = 768 * CC;
    if (i < S_WT) {
        int j = i >> 8, kk = i & 255;
        float w = (j < 256) ? Wq[kk * 256 + j] : Wkv[kk * 512 + (j - 256)];
        Wt[i] = f2bf(w);
        return;
    }
    i -= S_WT;
    const int S_WP = 256 * KP;
    if (i < S_WP) {
        int c2 = i / KP, t = i - c2 * KP;
        int h = t / VW, cc = t - h * VW;
        unsigned short v = 0;
        if (cc < 38) v = f2bf(Wpf[(h * 38 + cc) * 256 + c2]);
        Wpft[i] = v;
        return;
    }
    i -= S_WP;
    const int S_POS = BHN * 16 * NN;
    if (i < S_POS) {
        int n = i % NN;
        int r = i / NN;
        int bh = r >> 4;
        int c = (r & 15) + 32;
        float val = 0.f;
        if (c < 38) {
            float p3 = -1.f + 2.f * (float)(n % 48) / 47.f;
            float p4 = -1.f + 2.f * (float)(n / 48) / 63.f;
            float pv[6] = { p3 * p3, p4 * p4, p3 * p4, p3, p4, 1.f };
            val = pv[c - 32];
        }
        v2pT[((size_t)bh * VW + c) * NN + n] = f2bf(val);
    }
}

// ---------------------------------------------------------------------------
// qkv
// ---------------------------------------------------------------------------
__global__ __launch_bounds__(256) void qkv_kernel(
    const unsigned short* __restrict__ x1b, const unsigned short* __restrict__ x2b,
    const unsigned short* __restrict__ Wt,
    unsigned short* __restrict__ qbh, unsigned short* __restrict__ kbh,
    unsigned short* __restrict__ v2pT)
{
    int rt = blockIdx.x, ct = blockIdx.y;
    int wv = threadIdx.x >> 6, lane = threadIdx.x & 63;
    int g = lane >> 4, q = lane & 15;
    int row0 = rt * 64 + wv * 16;
    const unsigned short* A = (ct < 4) ? x1b : x2b;
    const unsigned short* arow = A + (size_t)(row0 + q) * CC + g * 8;
    const unsigned short* brow = Wt + (size_t)(ct * 64 + q) * CC + g * 8;
    f32x4 acc[4];
    #pragma unroll
    for (int cb = 0; cb < 4; ++cb) acc[cb] = f32x4{0.f, 0.f, 0.f, 0.f};
    for (int k0 = 0; k0 < CC; k0 += 32) {
        bf16x8 af = ldb8(arow + k0);
        #pragma unroll
        for (int cb = 0; cb < 4; ++cb)
            acc[cb] = mfma16(af, ldb8(brow + (size_t)cb * 16 * CC + k0), acc[cb]);
    }
    int b = row0 / NN, nb = row0 % NN;
    #pragma unroll
    for (int cb = 0; cb < 4; ++cb) {
        int jj = ct * 64 + cb * 16 + q;
        #pragma unroll
        for (int r = 0; r < 4; ++r) {
            int n = nb + 4 * g + r;
            unsigned short bv = f2bf(acc[cb][r]);
            if (jj < 256) {
                int h = jj >> 5, c = jj & 31;
                qbh[(size_t)((b * NH + h) * NN + n) * DD + c] = bv;
            } else if (jj < 512) {
                int jk = jj - 256; int h = jk >> 5, c = jk & 31;
                kbh[(size_t)((b * NH + h) * NN + n) * DD + c] = bv;
            } else {
                int jv = jj - 512; int h = jv >> 5, c = jv & 31;
                v2pT[(size_t)((b * NH + h) * VW + c) * NN + n] = bv;
            }
        }
    }
}

// ---------------------------------------------------------------------------
// fused attention v13: R7 structure + STORE PACING via double-buffered tile.
// Each wave: [2][16][256] bf16 tile. Phase ph fills buf[ph&1]; its 8
// iterations each issue (after the 5 prefetch loads, before compute) 2 NT
// stores draining buf[(ph-1)&1] rows 2*it2, 2*it2+1. The vmcnt FIFO is
// [5L][2S][5L][2S]... so a load's use waits behind at most 2 stores, each
// with ~2 iterations of ack slack — removing R5/R7's once-per-phase
// 16-store drain stall (the last untested mechanism).
// ---------------------------------------------------------------------------
__global__ __launch_bounds__(256) void attn_kernel(
    const unsigned short* __restrict__ qbh, const unsigned short* __restrict__ kbh,
    const unsigned short* __restrict__ v2pT,
    float* __restrict__ out, unsigned short* __restrict__ yacc)
{
    __shared__ unsigned short ptile[4][2][16][256];   // 64 KB
    const float C = 0.17677669529663687f * 1.4426950408889634f;  // scale*log2e

    // XCD-bijective swizzle (neutral, kept): 768 % 8 == 0
    int id = blockIdx.x;
    int xcd = id & 7;
    int slot = id >> 3;                 // 0..95
    int bh = xcd * 2 + (slot & 1);      // 0..15
    int qt = slot >> 1;                 // 0..47

    int wv = threadIdx.x >> 6, lane = threadIdx.x & 63;
    int g = lane >> 4, q = lane & 15;
    int qrow = qt * 64 + wv * 16;

    bf16x8 qf = ldb8(qbh + (size_t)(bh * NN + qrow + q) * DD + g * 8);
    const unsigned short* kbase = kbh + (size_t)bh * NN * DD;
    const unsigned short* vbase = v2pT + (size_t)bh * VW * NN;

    // ---- pass A: row sums of exp ----
    float l = 0.f;
    {
        bf16x8 kf0 = ldb8(kbase + (size_t)(q) * DD + g * 8);
        bf16x8 kf1 = ldb8(kbase + (size_t)(16 + q) * DD + g * 8);
        for (int it = 0; it < 96; ++it) {
            int m0 = it * 32;
            bf16x8 kn0 = ldb8(kbase + (size_t)(m0 + 32 + q) * DD + g * 8);
            bf16x8 kn1 = ldb8(kbase + (size_t)(m0 + 48 + q) * DD + g * 8);
            f32x4 z = {0.f, 0.f, 0.f, 0.f};
            f32x4 s0 = mfma16(kf0, qf, z);
            f32x4 s1 = mfma16(kf1, qf, z);
            #pragma unroll
            for (int r = 0; r < 4; ++r)
                l += exp2f(s0[r] * C) + exp2f(s1[r] * C);
            kf0 = kn0; kf1 = kn1;
        }
    }
    l += __shfl_xor(l, 16, 64);
    l += __shfl_xor(l, 32, 64);
    float nl2 = -__log2f(l);                  // p = exp2(s*C + nl2)

    // ---- pass B ----
    f32x4 yt0 = {0.f,0.f,0.f,0.f}, yt1 = yt0, yt2 = yt0;
    char* buf0 = (char*)&ptile[wv][0][0][0];     // 16 rows x 512 B each
    char* buf1 = (char*)&ptile[wv][1][0][0];
    unsigned swq = (unsigned)((q & 7) << 4);     // bank swizzle (XOR bytes 4..6)

    bf16x8 kf0 = ldb8(kbase + (size_t)(q) * DD + g * 8);
    bf16x8 kf1 = ldb8(kbase + (size_t)(16 + q) * DD + g * 8);
    bf16x8 vf0 = ldb8(vbase + (size_t)(q) * NN + g * 8);
    bf16x8 vf1 = ldb8(vbase + (size_t)(16 + q) * NN + g * 8);
    bf16x8 vf2 = ldb8(vbase + (size_t)(32 + q) * NN + g * 8);

    for (int ph = 0; ph < 12; ++ph) {
        char* fill  = (ph & 1) ? buf1 : buf0;
        char* drain = (ph & 1) ? buf0 : buf1;    // previous phase's tile
        char* prow = fill + q * 512;
        #pragma unroll
        for (int it2 = 0; it2 < 8; ++it2) {
            int m0 = ph * 256 + it2 * 32;
            // 1) prefetch loads for next iteration (first in this iter's FIFO)
            bf16x8 kn0 = ldb8(kbase + (size_t)(m0 + 32 + q) * DD + g * 8);
            bf16x8 kn1 = ldb8(kbase + (size_t)(m0 + 48 + q) * DD + g * 8);
            bf16x8 vn0 = ldb8(vbase + (size_t)(q) * NN + m0 + 32 + g * 8);
            bf16x8 vn1 = ldb8(vbase + (size_t)(16 + q) * NN + m0 + 32 + g * 8);
            bf16x8 vn2 = ldb8(vbase + (size_t)(32 + q) * NN + m0 + 32 + g * 8);
            // 2) paced drain: 2 NT stores of previous phase's rows
            if (ph > 0) {
                #pragma unroll
                for (int j = 0; j < 2; ++j) {
                    int r = it2 * 2 + j;
                    unsigned off = ((unsigned)(lane * 8)) ^ ((unsigned)((r & 7) << 4));
                    uint2 d = *(const uint2*)(drain + r * 512 + off);
                    f32x4 v;
                    v[0] = bflo2f(d.x); v[1] = bfhi2f(d.x);
                    v[2] = bflo2f(d.y); v[3] = bfhi2f(d.y);
                    float* dst = out + (size_t)(bh * NN + qrow + r) * OUTW
                               + (ph - 1) * 256 + lane * 4;
                    __builtin_nontemporal_store(v, (f32x4*)dst);
                }
            }
            // 3) compute
            f32x4 z = {0.f, 0.f, 0.f, 0.f};
            f32x4 s0 = mfma16(kf0, qf, z);
            f32x4 s1 = mfma16(kf1, qf, z);
            short4v pk0, pk1;
            #pragma unroll
            for (int r = 0; r < 4; ++r) {
                pk0[r] = (short)f2bf(exp2f(__builtin_fmaf(s0[r], C, nl2)));
                pk1[r] = (short)f2bf(exp2f(__builtin_fmaf(s1[r], C, nl2)));
            }
            unsigned b0 = (unsigned)(it2 * 64 + 8 * g);
            *(short4v*)(prow + (b0 ^ swq)) = pk0;
            *(short4v*)(prow + ((b0 + 32) ^ swq)) = pk1;
            asm volatile("s_waitcnt lgkmcnt(0)" ::: "memory");
            __builtin_amdgcn_sched_barrier(0);
            bf16x8 pf = *(const bf16x8*)(prow + ((unsigned)(it2 * 64 + 16 * g) ^ swq));
            yt0 = mfma16(vf0, pf, yt0);
            yt1 = mfma16(vf1, pf, yt1);
            yt2 = mfma16(vf2, pf, yt2);
            kf0 = kn0; kf1 = kn1; vf0 = vn0; vf1 = vn1; vf2 = vn2;
        }
    }
    // ---- tail drain: phase 11's tile (buf1) ----
    #pragma unroll
    for (int i = 0; i < 16; ++i) {
        unsigned off = ((unsigned)(lane * 8)) ^ ((unsigned)((i & 7) << 4));
        uint2 d = *(const uint2*)(buf1 + i * 512 + off);
        f32x4 v;
        v[0] = bflo2f(d.x); v[1] = bfhi2f(d.x);
        v[2] = bflo2f(d.y); v[3] = bfhi2f(d.y);
        float* dst = out + (size_t)(bh * NN + qrow + i) * OUTW + 11 * 256 + lane * 4;
        __builtin_nontemporal_store(v, (f32x4*)dst);
    }

    // ---- epilogue: y^T frag -> yacc[b*NN+n][h*48 + c] bf16 ----
    int b = bh >> 3, h = bh & 7;
    int nrow = qrow + q;
    unsigned short* yrow = yacc + (size_t)(b * NN + nrow) * KP + h * VW;
    f32x4 yts[3] = { yt0, yt1, yt2 };
    #pragma unroll
    for (int cb = 0; cb < 3; ++cb) {
        short4v pk;
        #pragma unroll
        for (int r = 0; r < 4; ++r) pk[r] = (short)f2bf(yts[cb][r]);
        *(short4v*)(yrow + cb * 16 + 4 * g) = pk;
    }
}

// ---------------------------------------------------------------------------
// proj
// ---------------------------------------------------------------------------
__global__ __launch_bounds__(256) void proj_kernel(
    const unsigned short* __restrict__ yacc, const unsigned short* __restrict__ Wpft,
    const float* __restrict__ bpf, float* __restrict__ out)
{
    int rt = blockIdx.x, ct = blockIdx.y;
    int wv = threadIdx.x >> 6, lane = threadIdx.x & 63;
    int g = lane >> 4, q = lane & 15;
    int row0 = rt * 64 + wv * 16;
    const unsigned short* arow = yacc + (size_t)(row0 + q) * KP + g * 8;
    const unsigned short* b0 = Wpft + (size_t)(ct * 64 + q) * KP + g * 8;
    f32x4 acc[4];
    #pragma unroll
    for (int cb = 0; cb < 4; ++cb) acc[cb] = f32x4{0.f, 0.f, 0.f, 0.f};
    for (int k0 = 0; k0 < KP; k0 += 32) {
        bf16x8 af = ldb8(arow + k0);
        #pragma unroll
        for (int cb = 0; cb < 4; ++cb)
            acc[cb] = mfma16(af, ldb8(b0 + (size_t)cb * 16 * KP + k0), acc[cb]);
    }
    int b = row0 / NN, nb = row0 % NN;
    #pragma unroll
    for (int cb = 0; cb < 4; ++cb) {
        int c2 = ct * 64 + cb * 16 + q;
        float bias = bpf[c2];
        int h = c2 >> 5, c = c2 & 31;
        float* obase = out + (size_t)((b * NH + h) * NN) * OUTW + NN + c;
        #pragma unroll
        for (int r = 0; r < 4; ++r) {
            int n = nb + 4 * g + r;
            __builtin_nontemporal_store(acc[cb][r] + bias, &obase[(size_t)n * OUTW]);
        }
    }
}

// ---------------------------------------------------------------------------
extern "C" void kernel_launch(void* const* d_in, const int* in_sizes, int n_in,
                              void* d_out, int out_size, void* d_ws, size_t ws_size,
                              hipStream_t stream)
{
    (void)in_sizes; (void)n_in; (void)out_size; (void)ws_size;
    const float* x1  = (const float*)d_in[0];
    const float* x2  = (const float*)d_in[1];
    const float* Wq  = (const float*)d_in[2];
    const float* Wkv = (const float*)d_in[3];
    const float* Wpf = (const float*)d_in[4];
    const float* bpf = (const float*)d_in[5];
    float* out = (float*)d_out;
    char* ws = (char*)d_ws;

    unsigned short* x1b  = (unsigned short*)(ws + 0);
    unsigned short* x2b  = (unsigned short*)(ws + 3145728);
    unsigned short* Wt   = (unsigned short*)(ws + 6291456);
    unsigned short* Wpft = (unsigned short*)(ws + 6684672);
    unsigned short* qbh  = (unsigned short*)(ws + 6881280);
    unsigned short* kbh  = (unsigned short*)(ws + 10027008);
    unsigned short* v2pT = (unsigned short*)(ws + 13172736);
    unsigned short* yacc = (unsigned short*)(ws + 17891328);

    prep_kernel<<<16512, 256, 0, stream>>>(x1, x2, Wq, Wkv, Wpf, x1b, x2b, Wt, Wpft, v2pT);
    qkv_kernel<<<dim3(96, 12), 256, 0, stream>>>(x1b, x2b, Wt, qbh, kbh, v2pT);
    attn_kernel<<<768, 256, 0, stream>>>(qbh, kbh, v2pT, out, yacc);
    proj_kernel<<<dim3(96, 4), 256, 0, stream>>>(yacc, Wpft, bpf, out);
}